// Round 4
// baseline (226.126 us; speedup 1.0000x reference)
//
#include <hip/hip_runtime.h>
#include <math.h>

#ifndef __has_builtin
#define __has_builtin(x) 0
#endif

#if __has_builtin(__builtin_amdgcn_rcpf)
#define FAST_RCP(x) __builtin_amdgcn_rcpf(x)
#else
#define FAST_RCP(x) (1.0f / (x))
#endif

#if __has_builtin(__builtin_amdgcn_exp2f)
#define FAST_EXP2(x) __builtin_amdgcn_exp2f(x)
#else
#define FAST_EXP2(x) exp2f(x)
#endif

typedef _Float16 half8 __attribute__((ext_vector_type(8)));
typedef _Float16 half2v __attribute__((ext_vector_type(2)));
typedef float f32x4 __attribute__((ext_vector_type(4)));
typedef float f32x2 __attribute__((ext_vector_type(2)));

constexpr int T_STEPS = 180;
constexpr int I_DIM   = 7;
constexpr int HDIM    = 64;
constexpr int BT      = 16;     // batch tile per GROUP
constexpr int NGRP    = 2;      // independent groups per block (ILP-2)
constexpr int TCH     = 60;     // x-stage chunk length (3 chunks of 60 steps)
constexpr int NCH     = 12;     // 12 chunks x 8 halfs = 96 K rows
constexpr int CH_HALF = BT * 8; // halfs per chunk slice (=128)
constexpr int XSTR    = 136;    // halfs per xstage t-slice (17 granules)

// ---- R4: dual-recurrence ILP ----
// Grid is the occupancy cap (512 blocks / 256 CU = 2 blocks/CU): the serial
// recurrence chain (ds_read ~120cy -> MFMA dep chain -> trans cell chain)
// is exposed ~350cy x 180 steps with only 2 independent chains per SIMD.
// Fix: BT_block=32 as TWO INDEPENDENT 16-batch groups per block (grid 256,
// 1 block/CU, 8 waves). Each wave runs both groups' step bodies between
// barriers: group B's instructions fill group A's latency stalls (in-wave
// ILP, compiler-scheduled), and barrier count per unit work halves.
// Weights (afrag) are shared across groups; only acc/c/h state doubles.
// x is staged in 60-step LDS chunks (2 mid-kernel restages) so the
// steady-state loop still has ZERO vmem -> clean barriers (validated R2).
// Per-group structure unchanged from R1-R3 (all validated):
//  - chunk-major B operand, conflict-free ds_read_b128
//  - lane-blended bf0 (q==0 lanes read xstage directly)
//  - gate-pair A remap -> packed dual-f32 cell math (5 exp2 + 2 rcp /cell)
__global__ __launch_bounds__(512, 2) void lstm_mfma_kernel(
    const float* __restrict__ x,
    const float* __restrict__ W_ih,
    const float* __restrict__ W_hh,
    const float* __restrict__ b_ih,
    const float* __restrict__ b_hh,
    const float* __restrict__ W_fc,
    const float* __restrict__ b_fc,
    float* __restrict__ out) {
    __shared__ alignas(16) _Float16 Bbuf[NGRP][2][NCH][BT][8];
    __shared__ alignas(16) _Float16 xstage[NGRP][TCH * XSTR];
    __shared__ alignas(16) float hlds[NGRP][BT][HDIM + 4];

    const int tid  = (int)threadIdx.x;
    const int w    = tid >> 6;    // wave 0..7
    const int lane = tid & 63;
    const int q    = lane >> 4;   // quad 0..3
    const int n15  = lane & 15;   // batch col within group tile
    const long bbase = (long)blockIdx.x * (NGRP * BT);

    // ---- A fragments, scale-folded, gate-pair remap (shared by groups) ----
    half8 afrag[2][3];
#pragma unroll
    for (int pt = 0; pt < 2; ++pt) {
        const int gate = 2 * pt + ((n15 >> 1) & 1);
        const int unit = 8 * w + 2 * (n15 >> 2) + (n15 & 1);
        const int grow = gate * HDIM + unit;  // row in PyTorch [4H, *] params
        const float scl = (gate == 2) ? 2.88539008177792681472f
                                      : -1.44269504088896340736f;
#pragma unroll
        for (int kc = 0; kc < 3; ++kc) {
#pragma unroll
            for (int j = 0; j < 8; ++j) {
                const int k = kc * 32 + q * 8 + j;
                float v;
                if (k < I_DIM)            v = W_ih[grow * I_DIM + k];
                else if (k == I_DIM)      v = b_ih[grow] + b_hh[grow];
                else if (k < 8 + HDIM)    v = W_hh[grow * HDIM + (k - 8)];
                else                      v = 0.0f;
                afrag[pt][kc][j] = (_Float16)(scl * v);
            }
        }
    }

    // ---- x chunk staging: xstage[g] slice t: [n*8+i]=x, [n*8+7]=1 (bias) ----
#define STAGE_X(TC)                                                            \
    for (int idx = tid; idx < NGRP * BT * TCH * 8; idx += 512) {               \
        const int i = idx & 7;                                                 \
        const int n = (idx >> 3) & 15;                                         \
        const int t = (idx >> 7) % TCH;                                        \
        const int g = (idx >> 7) / TCH;                                        \
        float v = 1.0f;                                                        \
        if (i < I_DIM)                                                         \
            v = x[(bbase + g * BT + n) * (T_STEPS * I_DIM) +                   \
                  ((TC) * TCH + t) * I_DIM + i];                               \
        xstage[g][t * XSTR + n * 8 + i] = (_Float16)v;                         \
    }

    STAGE_X(0)
    // zero both groups' B buffers (h_0 = 0; pad chunks must not be NaN)
    for (int idx = tid; idx < NGRP * 2 * NCH * CH_HALF; idx += 512)
        ((_Float16*)Bbuf)[idx] = (_Float16)0.0f;
    __syncthreads();

    // cell ownership: units u0 = 8w+2q, u0+1 (adjacent)
    const int u0 = 8 * w + 2 * q;

    // hoisted LDS pointers per group/buffer
    const _Float16* const rbA0 = &Bbuf[0][0][q][n15][0];
    const _Float16* const rbA1 = &Bbuf[0][1][q][n15][0];
    const _Float16* const rbB0 = &Bbuf[1][0][q][n15][0];
    const _Float16* const rbB1 = &Bbuf[1][1][q][n15][0];
    half2v* const hwA0 = (half2v*)&Bbuf[0][0][1 + w][n15][2 * q];
    half2v* const hwA1 = (half2v*)&Bbuf[0][1][1 + w][n15][2 * q];
    half2v* const hwB0 = (half2v*)&Bbuf[1][0][1 + w][n15][2 * q];
    half2v* const hwB1 = (half2v*)&Bbuf[1][1][1 + w][n15][2 * q];
    const _Float16* const xsA = &xstage[0][n15 * 8];
    const _Float16* const xsB = &xstage[1][n15 * 8];
    const int xadv = (q == 0) ? 2 * XSTR : 0;

    f32x2 cpA = {0.0f, 0.0f}, hpA = {0.0f, 0.0f};
    f32x2 cpB = {0.0f, 0.0f}, hpB = {0.0f, 0.0f};
    const f32x4 zq = {0.0f, 0.0f, 0.0f, 0.0f};

    // Packed cell: A0={i0,i1,f0,f1}, A1={g0,g1,o0,o1} (exp2-ready pairs).
#define LSTM_CELL2(A0, A1, CP, HP)                                             \
    {                                                                          \
        f32x2 Ap, Fp, Ep, Op, Rp, Cp, rD;                                      \
        Ap[0] = FAST_EXP2(A0[0]); Ap[1] = FAST_EXP2(A0[1]);                    \
        Fp[0] = FAST_EXP2(A0[2]); Fp[1] = FAST_EXP2(A0[3]);                    \
        Ep[0] = FAST_EXP2(A1[0]); Ep[1] = FAST_EXP2(A1[1]);                    \
        const f32x2 Pp = (Ap + 1.0f) * (Ep + 1.0f);                            \
        const f32x2 Qp = Fp + 1.0f;                                            \
        const f32x2 PQ = Pp * Qp;                                              \
        Rp[0] = FAST_RCP(PQ[0]); Rp[1] = FAST_RCP(PQ[1]);                      \
        CP = (CP * Pp + (Ep - 1.0f) * Qp) * Rp;                                \
        Op[0] = FAST_EXP2(A1[2]); Op[1] = FAST_EXP2(A1[3]);                    \
        f32x2 cs = CP * 2.88539008177792681472f;                               \
        cs[0] = fminf(fmaxf(cs[0], -80.0f), 80.0f);                            \
        cs[1] = fminf(fmaxf(cs[1], -80.0f), 80.0f);                            \
        Cp[0] = FAST_EXP2(cs[0]); Cp[1] = FAST_EXP2(cs[1]);                    \
        const f32x2 Dp = (Op + 1.0f) * (Cp + 1.0f);                            \
        rD[0] = FAST_RCP(Dp[0]); rD[1] = FAST_RCP(Dp[1]);                      \
        HP = (Cp - 1.0f) * rD;                                                 \
    }

    // One timestep for BOTH groups, single barrier. Reads issued first (6x
    // ds_read_b128, latency overlapped), MFMAs interleaved A/B, cells A/B.
#define LSTM_STEP2(XBA, RBA, HWA, XBB, RBB, HWB)                               \
    {                                                                          \
        const half8 bA0 = *(const half8*)(XBA);                                \
        const half8 bA1 = *(const half8*)((RBA) + 4 * CH_HALF);                \
        const half8 bA2 = *(const half8*)((RBA) + 8 * CH_HALF);                \
        const half8 bB0 = *(const half8*)(XBB);                                \
        const half8 bB1 = *(const half8*)((RBB) + 4 * CH_HALF);                \
        const half8 bB2 = *(const half8*)((RBB) + 8 * CH_HALF);                \
        f32x4 aA0 = __builtin_amdgcn_mfma_f32_16x16x32_f16(afrag[0][0], bA0, zq, 0, 0, 0); \
        f32x4 aB0 = __builtin_amdgcn_mfma_f32_16x16x32_f16(afrag[0][0], bB0, zq, 0, 0, 0); \
        f32x4 aA1 = __builtin_amdgcn_mfma_f32_16x16x32_f16(afrag[1][0], bA0, zq, 0, 0, 0); \
        f32x4 aB1 = __builtin_amdgcn_mfma_f32_16x16x32_f16(afrag[1][0], bB0, zq, 0, 0, 0); \
        aA0 = __builtin_amdgcn_mfma_f32_16x16x32_f16(afrag[0][1], bA1, aA0, 0, 0, 0); \
        aB0 = __builtin_amdgcn_mfma_f32_16x16x32_f16(afrag[0][1], bB1, aB0, 0, 0, 0); \
        aA1 = __builtin_amdgcn_mfma_f32_16x16x32_f16(afrag[1][1], bA1, aA1, 0, 0, 0); \
        aB1 = __builtin_amdgcn_mfma_f32_16x16x32_f16(afrag[1][1], bB1, aB1, 0, 0, 0); \
        aA0 = __builtin_amdgcn_mfma_f32_16x16x32_f16(afrag[0][2], bA2, aA0, 0, 0, 0); \
        aB0 = __builtin_amdgcn_mfma_f32_16x16x32_f16(afrag[0][2], bB2, aB0, 0, 0, 0); \
        aA1 = __builtin_amdgcn_mfma_f32_16x16x32_f16(afrag[1][2], bA2, aA1, 0, 0, 0); \
        aB1 = __builtin_amdgcn_mfma_f32_16x16x32_f16(afrag[1][2], bB2, aB1, 0, 0, 0); \
        LSTM_CELL2(aA0, aA1, cpA, hpA)                                         \
        LSTM_CELL2(aB0, aB1, cpB, hpB)                                         \
        *(HWA) = (half2v){(_Float16)hpA[0], (_Float16)hpA[1]};                 \
        *(HWB) = (half2v){(_Float16)hpB[0], (_Float16)hpB[1]};                 \
        __syncthreads();                                                       \
    }

    for (int tc = 0; tc < T_STEPS / TCH; ++tc) {
        if (tc) {              // restage next 60-step x chunk (rare vmem)
            STAGE_X(tc)
            __syncthreads();
        }
        const _Float16* xbA0 = (q == 0) ? xsA : rbA0;
        const _Float16* xbA1 = (q == 0) ? xsA + XSTR : rbA1;
        const _Float16* xbB0 = (q == 0) ? xsB : rbB0;
        const _Float16* xbB1 = (q == 0) ? xsB + XSTR : rbB1;
        for (int tt = 0; tt < TCH; tt += 2) {
            LSTM_STEP2(xbA0, rbA0, hwA1, xbB0, rbB0, hwB1)  // buf0 -> buf1
            LSTM_STEP2(xbA1, rbA1, hwA0, xbB1, rbB1, hwB0)  // buf1 -> buf0
            xbA0 += xadv; xbA1 += xadv; xbB0 += xadv; xbB1 += xadv;
        }
    }
#undef LSTM_STEP2
#undef LSTM_CELL2
#undef STAGE_X

    // ---- epilogue: out[b][j] = b_fc[j] + sum_u h[b][u] * W_fc[j][u] ----
    *(f32x2*)&hlds[0][n15][u0] = hpA;
    *(f32x2*)&hlds[1][n15][u0] = hpB;
    __syncthreads();
    {
        const int g = tid >> 8, b = (tid >> 4) & 15, j = tid & 15;
        float s = b_fc[j];
#pragma unroll 8
        for (int u = 0; u < HDIM; ++u)
            s += hlds[g][b][u] * W_fc[j * HDIM + u];
        out[(bbase + g * BT + b) * 16 + j] = s;
    }
}

extern "C" void kernel_launch(void* const* d_in, const int* in_sizes, int n_in,
                              void* d_out, int out_size, void* d_ws, size_t ws_size,
                              hipStream_t stream) {
    const float* x    = (const float*)d_in[0];
    const float* W_ih = (const float*)d_in[1];
    const float* W_hh = (const float*)d_in[2];
    const float* b_ih = (const float*)d_in[3];
    const float* b_hh = (const float*)d_in[4];
    const float* W_fc = (const float*)d_in[5];
    const float* b_fc = (const float*)d_in[6];
    float* out = (float*)d_out;

    const int B = in_sizes[0] / (T_STEPS * I_DIM);  // 8192
    const int grid = B / (NGRP * BT);                // 256 blocks (1/CU)

    lstm_mfma_kernel<<<grid, 512, 0, stream>>>(x, W_ih, W_hh, b_ih, b_hh,
                                               W_fc, b_fc, out);
}

// Round 5
// 212.330 us; speedup vs baseline: 1.0650x; 1.0650x over previous
//
#include <hip/hip_runtime.h>
#include <math.h>

#ifndef __has_builtin
#define __has_builtin(x) 0
#endif

#if __has_builtin(__builtin_amdgcn_rcpf)
#define FAST_RCP(x) __builtin_amdgcn_rcpf(x)
#else
#define FAST_RCP(x) (1.0f / (x))
#endif

#if __has_builtin(__builtin_amdgcn_exp2f)
#define FAST_EXP2(x) __builtin_amdgcn_exp2f(x)
#else
#define FAST_EXP2(x) exp2f(x)
#endif

typedef _Float16 half8 __attribute__((ext_vector_type(8)));
typedef _Float16 half2v __attribute__((ext_vector_type(2)));
typedef float f32x4 __attribute__((ext_vector_type(4)));
typedef float f32x2 __attribute__((ext_vector_type(2)));

constexpr int T_STEPS = 180;
constexpr int I_DIM   = 7;
constexpr int HDIM    = 64;
constexpr int BT      = 16;     // batch tile per block
constexpr int TCH     = 90;     // x-stage chunk length (2 chunks of 90 steps)
constexpr int NCH     = 12;     // 12 chunks x 8 halfs = 96 K rows
constexpr int CH_HALF = BT * 8; // halfs per chunk slice (=128)
constexpr int XSTR    = 136;    // halfs per xstage t-slice (17 granules)

// ---- R5: 4 small blocks per CU (anti-phase doubling) ----
// R4 lesson: 1 block/CU exposes every barrier drain (-30%); 2 blocks/CU
// (R3) was the load-bearing overlap. This round: 256-thread blocks (4
// waves), BT=16, grid 512 -> 4 blocks/CU, SAME 16 waves/CU. Each SIMD now
// hosts 4 waves from 4 INDEPENDENT blocks (vs 2) -> barrier/chain windows
// of one block are filled by three others; barrier width halves (4 waves).
// Per wave: 4 A-tiles (16 units) -> 12 MFMAs + 2 packed cell-pairs, but
// still only 3 ds_read_b128 (B shared across tiles: read amortization 2x).
// All validated structure kept: chunk-major conflict-free B reads (R1),
// zero-vmem steady loop + lane-blended x (R2), gate-pair remap + packed
// dual-f32 cell math (R3). x staged in 90-step chunks (1 restage).
// A-row remap (4 tiles): tile pt, A-row r ->
//   gate = 2*(pt&1) + ((r>>1)&1), unit = 16w + 8*(pt>>1) + 2*(r>>2) + (r&1)
// Thread (q,n15) cells: pair p in {0,1} -> units 16w+8p+2q+{0,1};
// acc(2p)={i0,i1,f0,f1}, acc(2p+1)={g0,g1,o0,o1} straight from MFMA.
// h-write for pair p: chunk 1+2w+p, row n15, halfs [2q,2q+1] -> the wave's
// 64 lanes cover 64 consecutive dwords per pair: conflict-free.
__global__ __launch_bounds__(256, 4) void lstm_mfma_kernel(
    const float* __restrict__ x,
    const float* __restrict__ W_ih,
    const float* __restrict__ W_hh,
    const float* __restrict__ b_ih,
    const float* __restrict__ b_hh,
    const float* __restrict__ W_fc,
    const float* __restrict__ b_fc,
    float* __restrict__ out) {
    __shared__ alignas(16) _Float16 Bbuf[2][NCH][BT][8];
    __shared__ alignas(16) _Float16 xstage[TCH * XSTR];
    __shared__ alignas(16) float hlds[BT][HDIM + 4];

    const int tid  = (int)threadIdx.x;
    const int w    = tid >> 6;    // wave 0..3
    const int lane = tid & 63;
    const int q    = lane >> 4;   // quad 0..3
    const int n15  = lane & 15;   // batch col within tile
    const long bbase = (long)blockIdx.x * BT;

    // ---- A fragments, scale-folded, 4-tile gate-pair remap ----
    half8 afrag[4][3];
#pragma unroll
    for (int pt = 0; pt < 4; ++pt) {
        const int gate = 2 * (pt & 1) + ((n15 >> 1) & 1);
        const int unit = 16 * w + 8 * (pt >> 1) + 2 * (n15 >> 2) + (n15 & 1);
        const int grow = gate * HDIM + unit;  // row in PyTorch [4H, *] params
        const float scl = (gate == 2) ? 2.88539008177792681472f
                                      : -1.44269504088896340736f;
#pragma unroll
        for (int kc = 0; kc < 3; ++kc) {
#pragma unroll
            for (int j = 0; j < 8; ++j) {
                const int k = kc * 32 + q * 8 + j;
                float v;
                if (k < I_DIM)            v = W_ih[grow * I_DIM + k];
                else if (k == I_DIM)      v = b_ih[grow] + b_hh[grow];
                else if (k < 8 + HDIM)    v = W_hh[grow * HDIM + (k - 8)];
                else                      v = 0.0f;
                afrag[pt][kc][j] = (_Float16)(scl * v);
            }
        }
    }

    // ---- x chunk staging: slice t: [n*8+i]=x_t[n][i] (i<7), [n*8+7]=1 ----
#define STAGE_X(TC)                                                            \
    for (int idx = tid; idx < BT * TCH * 8; idx += 256) {                      \
        const int i = idx & 7;                                                 \
        const int n = (idx >> 3) & 15;                                         \
        const int t = idx >> 7;                                                \
        float v = 1.0f;                                                        \
        if (i < I_DIM)                                                         \
            v = x[(bbase + n) * (T_STEPS * I_DIM) +                            \
                  ((TC) * TCH + t) * I_DIM + i];                               \
        xstage[t * XSTR + n * 8 + i] = (_Float16)v;                            \
    }

    STAGE_X(0)
    // zero both B buffers (h_0 = 0; pad chunks must not be NaN)
    for (int idx = tid; idx < 2 * NCH * CH_HALF; idx += 256)
        ((_Float16*)Bbuf)[idx] = (_Float16)0.0f;
    __syncthreads();

    // hoisted LDS pointers
    const _Float16* const rb0 = &Bbuf[0][q][n15][0];
    const _Float16* const rb1 = &Bbuf[1][q][n15][0];
    half2v* const hwA0 = (half2v*)&Bbuf[0][1 + 2 * w + 0][n15][2 * q];  // p=0
    half2v* const hwA1 = (half2v*)&Bbuf[1][1 + 2 * w + 0][n15][2 * q];
    half2v* const hwB0 = (half2v*)&Bbuf[0][1 + 2 * w + 1][n15][2 * q];  // p=1
    half2v* const hwB1 = (half2v*)&Bbuf[1][1 + 2 * w + 1][n15][2 * q];
    const _Float16* const xs = &xstage[n15 * 8];
    const int xadv = (q == 0) ? 2 * XSTR : 0;

    f32x2 cp0 = {0.0f, 0.0f}, hp0 = {0.0f, 0.0f};
    f32x2 cp1 = {0.0f, 0.0f}, hp1 = {0.0f, 0.0f};
    const f32x4 zq = {0.0f, 0.0f, 0.0f, 0.0f};

    // Packed cell pair: A0={i0,i1,f0,f1}, A1={g0,g1,o0,o1} (exp2-ready).
#define LSTM_CELL2(A0, A1, CP, HP)                                             \
    {                                                                          \
        f32x2 Ap, Fp, Ep, Op, Rp, Cp, rD;                                      \
        Ap[0] = FAST_EXP2(A0[0]); Ap[1] = FAST_EXP2(A0[1]);                    \
        Fp[0] = FAST_EXP2(A0[2]); Fp[1] = FAST_EXP2(A0[3]);                    \
        Ep[0] = FAST_EXP2(A1[0]); Ep[1] = FAST_EXP2(A1[1]);                    \
        const f32x2 Pp = (Ap + 1.0f) * (Ep + 1.0f);                            \
        const f32x2 Qp = Fp + 1.0f;                                            \
        const f32x2 PQ = Pp * Qp;                                              \
        Rp[0] = FAST_RCP(PQ[0]); Rp[1] = FAST_RCP(PQ[1]);                      \
        CP = (CP * Pp + (Ep - 1.0f) * Qp) * Rp;                                \
        Op[0] = FAST_EXP2(A1[2]); Op[1] = FAST_EXP2(A1[3]);                    \
        f32x2 cs = CP * 2.88539008177792681472f;                               \
        cs[0] = fminf(fmaxf(cs[0], -80.0f), 80.0f);                            \
        cs[1] = fminf(fmaxf(cs[1], -80.0f), 80.0f);                            \
        Cp[0] = FAST_EXP2(cs[0]); Cp[1] = FAST_EXP2(cs[1]);                    \
        const f32x2 Dp = (Op + 1.0f) * (Cp + 1.0f);                            \
        rD[0] = FAST_RCP(Dp[0]); rD[1] = FAST_RCP(Dp[1]);                      \
        HP = (Cp - 1.0f) * rD;                                                 \
    }

    // One timestep: 3 shared ds_read_b128 feed 12 MFMAs (4 indep acc
    // chains), 2 indep packed cell-pairs, 2 h-writes, 1 barrier.
#define LSTM_STEP(RB, XB, HWA, HWB)                                            \
    {                                                                          \
        const half8 bf0 = *(const half8*)(XB);                                 \
        const half8 bf1 = *(const half8*)((RB) + 4 * CH_HALF);                 \
        const half8 bf2 = *(const half8*)((RB) + 8 * CH_HALF);                 \
        f32x4 a00 = __builtin_amdgcn_mfma_f32_16x16x32_f16(afrag[0][0], bf0, zq, 0, 0, 0); \
        f32x4 a01 = __builtin_amdgcn_mfma_f32_16x16x32_f16(afrag[1][0], bf0, zq, 0, 0, 0); \
        f32x4 a10 = __builtin_amdgcn_mfma_f32_16x16x32_f16(afrag[2][0], bf0, zq, 0, 0, 0); \
        f32x4 a11 = __builtin_amdgcn_mfma_f32_16x16x32_f16(afrag[3][0], bf0, zq, 0, 0, 0); \
        a00 = __builtin_amdgcn_mfma_f32_16x16x32_f16(afrag[0][1], bf1, a00, 0, 0, 0); \
        a01 = __builtin_amdgcn_mfma_f32_16x16x32_f16(afrag[1][1], bf1, a01, 0, 0, 0); \
        a10 = __builtin_amdgcn_mfma_f32_16x16x32_f16(afrag[2][1], bf1, a10, 0, 0, 0); \
        a11 = __builtin_amdgcn_mfma_f32_16x16x32_f16(afrag[3][1], bf1, a11, 0, 0, 0); \
        a00 = __builtin_amdgcn_mfma_f32_16x16x32_f16(afrag[0][2], bf2, a00, 0, 0, 0); \
        a01 = __builtin_amdgcn_mfma_f32_16x16x32_f16(afrag[1][2], bf2, a01, 0, 0, 0); \
        a10 = __builtin_amdgcn_mfma_f32_16x16x32_f16(afrag[2][2], bf2, a10, 0, 0, 0); \
        a11 = __builtin_amdgcn_mfma_f32_16x16x32_f16(afrag[3][2], bf2, a11, 0, 0, 0); \
        LSTM_CELL2(a00, a01, cp0, hp0)                                         \
        LSTM_CELL2(a10, a11, cp1, hp1)                                         \
        *(HWA) = (half2v){(_Float16)hp0[0], (_Float16)hp0[1]};                 \
        *(HWB) = (half2v){(_Float16)hp1[0], (_Float16)hp1[1]};                 \
        __syncthreads();                                                       \
    }

    for (int tc = 0; tc < T_STEPS / TCH; ++tc) {
        if (tc) {              // restage next 90-step x chunk (rare vmem)
            STAGE_X(tc)
            __syncthreads();
        }
        const _Float16* xb0 = (q == 0) ? xs : rb0;
        const _Float16* xb1 = (q == 0) ? xs + XSTR : rb1;
        for (int tt = 0; tt < TCH; tt += 2) {
            LSTM_STEP(rb0, xb0, hwA1, hwB1)   // read buf0, write buf1
            LSTM_STEP(rb1, xb1, hwA0, hwB0)   // read buf1, write buf0
            xb0 += xadv;
            xb1 += xadv;
        }
    }
#undef LSTM_STEP
#undef LSTM_CELL2
#undef STAGE_X

    // ---- epilogue: out[b][j] = b_fc[j] + sum_u h[b][u] * W_fc[j][u] ----
    *(f32x2*)&hlds[n15][16 * w + 2 * q]     = hp0;
    *(f32x2*)&hlds[n15][16 * w + 8 + 2 * q] = hp1;
    __syncthreads();
    {
        const int b = tid >> 4, j = tid & 15;   // 256 threads = full tile
        float s = b_fc[j];
#pragma unroll 8
        for (int u = 0; u < HDIM; ++u)
            s += hlds[b][u] * W_fc[j * HDIM + u];
        out[(bbase + b) * 16 + j] = s;
    }
}

extern "C" void kernel_launch(void* const* d_in, const int* in_sizes, int n_in,
                              void* d_out, int out_size, void* d_ws, size_t ws_size,
                              hipStream_t stream) {
    const float* x    = (const float*)d_in[0];
    const float* W_ih = (const float*)d_in[1];
    const float* W_hh = (const float*)d_in[2];
    const float* b_ih = (const float*)d_in[3];
    const float* b_hh = (const float*)d_in[4];
    const float* W_fc = (const float*)d_in[5];
    const float* b_fc = (const float*)d_in[6];
    float* out = (float*)d_out;

    const int B = in_sizes[0] / (T_STEPS * I_DIM);  // 8192
    const int grid = B / BT;                         // 512 blocks (4/CU)

    lstm_mfma_kernel<<<grid, 256, 0, stream>>>(x, W_ih, W_hh, b_ih, b_hh,
                                               W_fc, b_fc, out);
}